// Round 8
// baseline (161.271 us; speedup 1.0000x reference)
//
#include <hip/hip_runtime.h>
#include <hip/hip_bf16.h>
#include <math.h>

// Problem constants
#define B_  2
#define L_  2048
#define S_  2048
#define D_  256
#define H_  8
#define HD_ 32
#define ML_ (B_ * L_)
#define MS_ (B_ * S_)
#define NSPLIT 2
#define SCHUNK (S_ / NSPLIT)   // 1024

typedef __attribute__((ext_vector_type(8))) short short8;   // 8 bf16 (A/B frag)
typedef __attribute__((ext_vector_type(4))) float f32x4;    // C/D frag

// ---------------------------------------------------------------------------
// One-shot fp32 -> bf16 conversion of all GEMM operands. (Proven r3 path.)
// ---------------------------------------------------------------------------
__global__ __launch_bounds__(256) void convert_all(
    const float* __restrict__ x,  const float* __restrict__ src,
    const float* __restrict__ Wq, const float* __restrict__ Wk,
    const float* __restrict__ Wv, const float* __restrict__ Wm,
    const float* __restrict__ W1, const float* __restrict__ W2,
    __hip_bfloat16* xb,  __hip_bfloat16* srcb,
    __hip_bfloat16* Wqb, __hip_bfloat16* Wkb,
    __hip_bfloat16* Wvb, __hip_bfloat16* Wmb,
    __hip_bfloat16* W1b, __hip_bfloat16* W2b) {
    const size_t i4 = ((size_t)blockIdx.x * 256 + threadIdx.x) * 4;
    const float* sp; __hip_bfloat16* dp; size_t off;
    if      (i4 < 1048576) { sp = x;   dp = xb;   off = i4; }
    else if (i4 < 2097152) { sp = src; dp = srcb; off = i4 - 1048576; }
    else if (i4 < 2162688) { sp = Wq;  dp = Wqb;  off = i4 - 2097152; }
    else if (i4 < 2228224) { sp = Wk;  dp = Wkb;  off = i4 - 2162688; }
    else if (i4 < 2293760) { sp = Wv;  dp = Wvb;  off = i4 - 2228224; }
    else if (i4 < 2359296) { sp = Wm;  dp = Wmb;  off = i4 - 2293760; }
    else if (i4 < 2621440) { sp = W1;  dp = W1b;  off = i4 - 2359296; }
    else                   { sp = W2;  dp = W2b;  off = i4 - 2621440; }
    float4 v = *(const float4*)(sp + off);
    __hip_bfloat16 o0 = __float2bfloat16(v.x), o1 = __float2bfloat16(v.y);
    __hip_bfloat16 o2 = __float2bfloat16(v.z), o3 = __float2bfloat16(v.w);
    __hip_bfloat16* d = dp + off;
    d[0] = o0; d[1] = o1; d[2] = o2; d[3] = o3;
}

// ---------------------------------------------------------------------------
// r19: 128x64-tile MFMA GEMM body (4 waves, 64x32 per wave = 4x2 frags).
// Per K-step per wave: 16 MFMA vs 12 ds_read_b128 (was 8:8 at 64x64), and
// staging bytes per MFMA halve — the m92->m93 ladder step applied to proj.
// Same fragment mappings / pad-72 LDS / dbuf-prefetch loop as the proven body.
// ---------------------------------------------------------------------------
__device__ __forceinline__ void gemm_body128(const __hip_bfloat16* __restrict__ A,
                                             const __hip_bfloat16* __restrict__ Bm,
                                             __hip_bfloat16* __restrict__ C,
                                             int N, int K, int lda, int m0, int n0,
                                             float cscale,
                                             __hip_bfloat16 (&As)[128][72],
                                             __hip_bfloat16 (&Bs)[64][72]) {
    const int tid  = threadIdx.x;
    const int w    = tid >> 6;
    const int lane = tid & 63;
    const int colL = lane & 15;
    const int quad = lane >> 4;
    const int wm = (w & 1) * 64;      // wave M-offset (0/64)
    const int wn = (w >> 1) * 32;     // wave N-offset (0/32)
    const int srow = tid >> 3;        // 0..31
    const int scg  = (tid & 7) * 8;   // 0..56

    f32x4 acc[4][2] = {};

    auto loadA = [&](int p, int k0) -> short8 {
        return *(const short8*)(A + (size_t)(m0 + srow + p * 32) * lda + k0 + scg);
    };
    auto loadB = [&](int p, int k0) -> short8 {
        return *(const short8*)(Bm + (size_t)(n0 + srow + p * 32) * K + k0 + scg);
    };

    short8 ra[4], rb[2];
#pragma unroll
    for (int p = 0; p < 4; ++p) ra[p] = loadA(p, 0);
#pragma unroll
    for (int p = 0; p < 2; ++p) rb[p] = loadB(p, 0);

    for (int k0 = 0; k0 < K; k0 += 64) {
        __syncthreads();
#pragma unroll
        for (int p = 0; p < 4; ++p)
            *(short8*)&As[srow + p * 32][scg] = ra[p];
#pragma unroll
        for (int p = 0; p < 2; ++p)
            *(short8*)&Bs[srow + p * 32][scg] = rb[p];
        __syncthreads();
        if (k0 + 64 < K) {
#pragma unroll
            for (int p = 0; p < 4; ++p) ra[p] = loadA(p, k0 + 64);
#pragma unroll
            for (int p = 0; p < 2; ++p) rb[p] = loadB(p, k0 + 64);
        }
#pragma unroll
        for (int ks = 0; ks < 2; ++ks) {
            short8 af[4], bf[2];
#pragma unroll
            for (int i = 0; i < 4; ++i)
                af[i] = *(const short8*)&As[wm + i * 16 + colL][ks * 32 + quad * 8];
#pragma unroll
            for (int j = 0; j < 2; ++j)
                bf[j] = *(const short8*)&Bs[wn + j * 16 + colL][ks * 32 + quad * 8];
#pragma unroll
            for (int i = 0; i < 4; ++i)
#pragma unroll
                for (int j = 0; j < 2; ++j)
                    acc[i][j] = __builtin_amdgcn_mfma_f32_16x16x32_bf16(af[i], bf[j], acc[i][j], 0, 0, 0);
        }
    }
#pragma unroll
    for (int i = 0; i < 4; ++i)
#pragma unroll
        for (int r = 0; r < 4; ++r) {
            const size_t row = m0 + wm + i * 16 + quad * 4 + r;
#pragma unroll
            for (int j = 0; j < 2; ++j) {
                float v = acc[i][j][r] * cscale;
                C[row * N + n0 + wn + j * 16 + colL] = (__hip_bfloat16)v;
            }
        }
}

// ---------------------------------------------------------------------------
// Fused Q/K/Vt projection GEMMs, r19: 128x64 tiles, 384 blocks.
//   id 0..127   : Q = x @ Wq^T   (4096x256, 32x4 tiles), pre-scaled 1/sqrt(hd)
//   id 128..255 : K = src @ Wk^T (4096x256)
//   id 256..383 : Vt[b] = Wv @ src[b]^T (256x2048 per batch, 2x32 tiles x2)
// ---------------------------------------------------------------------------
__global__ __launch_bounds__(256) void proj_fused(const __hip_bfloat16* __restrict__ x_b,
                                                  const __hip_bfloat16* __restrict__ src_b,
                                                  const __hip_bfloat16* __restrict__ Wq_b,
                                                  const __hip_bfloat16* __restrict__ Wk_b,
                                                  const __hip_bfloat16* __restrict__ Wv_b,
                                                  __hip_bfloat16* __restrict__ Qb,
                                                  __hip_bfloat16* __restrict__ Kb,
                                                  __hip_bfloat16* __restrict__ Vtb) {
    __shared__ __hip_bfloat16 As[128][72];
    __shared__ __hip_bfloat16 Bs[64][72];
    const int id = blockIdx.x;
    if (id < 128) {
        gemm_body128(x_b, Wq_b, Qb, 256, 256, 256,
                     (id >> 2) * 128, (id & 3) * 64,
                     0.17677669529663687f, As, Bs);
    } else if (id < 256) {
        const int t = id - 128;
        gemm_body128(src_b, Wk_b, Kb, 256, 256, 256,
                     (t >> 2) * 128, (t & 3) * 64, 1.f, As, Bs);
    } else {
        const int t = id - 256;          // 0..127
        const int b = t >> 6, u = t & 63;
        gemm_body128(Wv_b, src_b + (size_t)b * S_ * D_,
                     Vtb + (size_t)b * D_ * S_, S_, 256, 256,
                     (u & 1) * 128, (u >> 1) * 64, 1.f, As, Bs);
    }
}

// ---------------------------------------------------------------------------
// Flash attention — round-0 proven inner loop, NSPLIT=2 (r18, neutral vs 4).
// Inner loop untouched (r14 lesson: structural attn edits are high-risk).
// ---------------------------------------------------------------------------
__global__ __launch_bounds__(256, 4) void attn_mfma(const __hip_bfloat16* __restrict__ Qb,
                                                    const __hip_bfloat16* __restrict__ Kb,
                                                    const __hip_bfloat16* __restrict__ Vtb,
                                                    const float* __restrict__ F,
                                                    __hip_bfloat16* __restrict__ Op,
                                                    float* __restrict__ Ll) {
    const int tid  = threadIdx.x;
    const int w    = tid >> 6;
    const int lane = tid & 63;
    const int colL = lane & 15;
    const int quad = lane >> 4;

    const int b     = blockIdx.z / NSPLIT;
    const int split = blockIdx.z % NSPLIT;
    const int h     = blockIdx.y;
    const int qw    = blockIdx.x * 64 + w * 16;

    __shared__ __hip_bfloat16 Ks[128][40];
    __shared__ __hip_bfloat16 Vs[32][136];
    __shared__ __hip_bfloat16 Pw[4][16][72];

    const short8 aq = *(const short8*)(Qb + ((size_t)(b * L_ + qw + colL)) * D_ + h * HD_ + quad * 8);

    float lsum[4] = {0.f, 0.f, 0.f, 0.f};
    f32x4 o0 = {0.f, 0.f, 0.f, 0.f}, o1 = {0.f, 0.f, 0.f, 0.f};

    const int kr = tid >> 2, kc = (tid & 3) * 8;
    const int vr = tid >> 3, vc = (tid & 7) * 8;
    const __hip_bfloat16* kst = Kb + ((size_t)(b * S_ + kr)) * D_ + h * HD_ + kc;
    const __hip_bfloat16* vst = Vtb + (size_t)b * D_ * S_ + ((size_t)(h * HD_ + vr)) * S_ + vc;
    const float* fbase = F + ((size_t)(b * L_ + qw + quad * 4)) * S_ + colL;

    const int sbeg = split * SCHUNK, send = sbeg + SCHUNK;
    short8 rk[2], rv[2];
#pragma unroll
    for (int p = 0; p < 2; ++p) {
        rk[p] = *(const short8*)(kst + (size_t)(sbeg + p * 64) * D_);
        rv[p] = *(const short8*)(vst + sbeg + p * 64);
    }

    for (int s0 = sbeg; s0 < send; s0 += 128) {
        __syncthreads();
        *(short8*)&Ks[kr][kc]        = rk[0];
        *(short8*)&Ks[kr + 64][kc]   = rk[1];
        *(short8*)&Vs[vr][vc]        = rv[0];
        *(short8*)&Vs[vr][vc + 64]   = rv[1];
        __syncthreads();
        if (s0 + 128 < send) {
#pragma unroll
            for (int p = 0; p < 2; ++p) {
                rk[p] = *(const short8*)(kst + (size_t)(s0 + 128 + p * 64) * D_);
                rv[p] = *(const short8*)(vst + s0 + 128 + p * 64);
            }
        }
#pragma unroll
        for (int hs = 0; hs < 2; ++hs) {
            const int sh = s0 + hs * 64;
            f32x4 cc[4];
#pragma unroll
            for (int n = 0; n < 4; ++n) {
                short8 kf = *(const short8*)&Ks[hs * 64 + n * 16 + colL][quad * 8];
                f32x4 z = {0.f, 0.f, 0.f, 0.f};
                cc[n] = __builtin_amdgcn_mfma_f32_16x16x32_bf16(aq, kf, z, 0, 0, 0);
            }
#pragma unroll
            for (int n = 0; n < 4; ++n)
#pragma unroll
                for (int r = 0; r < 4; ++r) {
                    float fv = fbase[(size_t)r * S_ + sh + n * 16];
                    float p = __expf(cc[n][r] * fv);
                    lsum[r] += p;
                    Pw[w][quad * 4 + r][n * 16 + colL] = __float2bfloat16(p);
                }
            short8 a0 = *(const short8*)(&Pw[w][colL][quad * 8]);
            short8 a1 = *(const short8*)(&Pw[w][colL][32 + quad * 8]);
#pragma unroll
            for (int ks = 0; ks < 2; ++ks) {
                short8 ap = ks ? a1 : a0;
#pragma unroll
                for (int nt = 0; nt < 2; ++nt) {
                    short8 vf = *(const short8*)&Vs[nt * 16 + colL][hs * 64 + ks * 32 + quad * 8];
                    if (nt == 0) o0 = __builtin_amdgcn_mfma_f32_16x16x32_bf16(ap, vf, o0, 0, 0, 0);
                    else         o1 = __builtin_amdgcn_mfma_f32_16x16x32_bf16(ap, vf, o1, 0, 0, 0);
                }
            }
        }
    }

#pragma unroll
    for (int r = 0; r < 4; ++r) {
        float t = lsum[r];
        t += __shfl_xor(t, 1);
        t += __shfl_xor(t, 2);
        t += __shfl_xor(t, 4);
        t += __shfl_xor(t, 8);
        lsum[r] = t;
    }

#pragma unroll
    for (int r = 0; r < 4; ++r) {
        const size_t row = (size_t)(b * L_ + qw + quad * 4 + r);
        const size_t po = ((size_t)split * ML_ + row) * D_ + h * HD_;
        Op[po + colL]      = __float2bfloat16(o0[r]);
        Op[po + 16 + colL] = __float2bfloat16(o1[r]);
        if (colL == 0)
            Ll[((size_t)split * H_ + h) * ML_ + row] = lsum[r];
    }
}

// ---------------------------------------------------------------------------
// MLP megakernel — r3-proven staged version (512 threads / 8 waves). Its
// local optimum: r15 (more waves) neutral, r16 (in-staging cvt) and r17
// (barrier-free direct B-loads) both regressed. Do not touch.
// ---------------------------------------------------------------------------
__global__ __launch_bounds__(512) void mlp_fused(const __hip_bfloat16* __restrict__ Opart,
                                                 const float* __restrict__ Ll,
                                                 const __hip_bfloat16* __restrict__ x_b,
                                                 const __hip_bfloat16* __restrict__ Wm_b,
                                                 const __hip_bfloat16* __restrict__ W1_b,
                                                 const __hip_bfloat16* __restrict__ W2_b,
                                                 const float* __restrict__ g1,
                                                 const float* __restrict__ b1,
                                                 const float* __restrict__ g2,
                                                 const float* __restrict__ b2,
                                                 const float* __restrict__ x,
                                                 float* __restrict__ out) {
    __shared__ __hip_bfloat16 Bs[256][72];     // 36864 B (shared by all phases)
    __shared__ __hip_bfloat16 As[16][72];      // 2304 B  (phase-1 A staging)
    __shared__ __hip_bfloat16 Acat[16][520];   // 16640 B [x | m1]
    __shared__ __hip_bfloat16 Hs[16][520];     // 16640 B h (512 cols used)
    __shared__ float gs[256], bs_[256];
    __shared__ float stats[8][16][2];
    __shared__ float Linv[16][8];

    const int tid  = threadIdx.x;
    const int w    = tid >> 6;        // 0..7
    const int lane = tid & 63;
    const int colL = lane & 15;
    const int quad = lane >> 4;
    const int nh   = w * 32;          // per-wave 32-col slice
    const int m0   = blockIdx.x * 16;
    const int srow = tid >> 3;        // 0..63
    const int scg  = (tid & 7) * 8;   // 0..56

    // ---- phase 0: params, Linv, x rows -> Acat[:,0:256] ----
    if (tid < 256) { gs[tid] = g1[tid]; bs_[tid] = b1[tid]; }
    if (tid < 128) {
        const int row = tid >> 3, hh = tid & 7;
        float t = 0.f;
#pragma unroll
        for (int s = 0; s < NSPLIT; ++s)
            t += Ll[((size_t)s * H_ + hh) * ML_ + m0 + row];
        Linv[row][hh] = 1.f / t;
    }
    if (tid < 256) {
        const int xr = tid >> 4, xc = (tid & 15) * 16;
        *(short8*)&Acat[xr][xc]     = *(const short8*)(x_b + (size_t)(m0 + xr) * 256 + xc);
        *(short8*)&Acat[xr][xc + 8] = *(const short8*)(x_b + (size_t)(m0 + xr) * 256 + xc + 8);
    }
    __syncthreads();

    // ---- phase 1: combine + Wm GEMM (K=256) ----
    f32x4 acc[2] = {};
    auto loadA1 = [&](int k0) -> short8 {     // srow < 16 only (tid < 128)
        const float inv = Linv[srow][(k0 + scg) >> 5];
        float a[8] = {};
#pragma unroll
        for (int s = 0; s < NSPLIT; ++s) {
            short8 v = *(const short8*)(Opart + ((size_t)s * ML_ + m0 + srow) * 256 + k0 + scg);
#pragma unroll
            for (int e = 0; e < 8; ++e) {
                union { short s16; __hip_bfloat16 h; } c; c.s16 = v[e];
                a[e] += __bfloat162float(c.h);
            }
        }
        short8 outv;
#pragma unroll
        for (int e = 0; e < 8; ++e) {
            union { __hip_bfloat16 h; short s16; } c;
            c.h = __float2bfloat16(a[e] * inv);
            outv[e] = c.s16;
        }
        return outv;
    };

    {
        short8 ra = {};
        if (srow < 16) ra = loadA1(0);
        short8 rb[4];
#pragma unroll
        for (int p = 0; p < 4; ++p)
            rb[p] = *(const short8*)(Wm_b + (size_t)(srow + p * 64) * 256 + scg);
        for (int k0 = 0; k0 < 256; k0 += 64) {
            __syncthreads();
            if (srow < 16) *(short8*)&As[srow][scg] = ra;
#pragma unroll
            for (int p = 0; p < 4; ++p)
                *(short8*)&Bs[srow + p * 64][scg] = rb[p];
            __syncthreads();
            if (k0 + 64 < 256) {
                if (srow < 16) ra = loadA1(k0 + 64);
#pragma unroll
                for (int p = 0; p < 4; ++p)
                    rb[p] = *(const short8*)(Wm_b + (size_t)(srow + p * 64) * 256 + k0 + 64 + scg);
            }
#pragma unroll
            for (int ks = 0; ks < 2; ++ks) {
                short8 af = *(const short8*)&As[colL][ks * 32 + quad * 8];
#pragma unroll
                for (int j = 0; j < 2; ++j) {
                    short8 bf = *(const short8*)&Bs[nh + j * 16 + colL][ks * 32 + quad * 8];
                    acc[j] = __builtin_amdgcn_mfma_f32_16x16x32_bf16(af, bf, acc[j], 0, 0, 0);
                }
            }
        }
    }
    // LN1 stats + write m1 into Acat[:,256:512]
#pragma unroll
    for (int r = 0; r < 4; ++r) {
        float s = 0.f, q = 0.f;
#pragma unroll
        for (int j = 0; j < 2; ++j) { float v = acc[j][r]; s += v; q += v * v; }
        s += __shfl_xor(s, 1); q += __shfl_xor(q, 1);
        s += __shfl_xor(s, 2); q += __shfl_xor(q, 2);
        s += __shfl_xor(s, 4); q += __shfl_xor(q, 4);
        s += __shfl_xor(s, 8); q += __shfl_xor(q, 8);
        if (colL == 0) { stats[w][quad * 4 + r][0] = s; stats[w][quad * 4 + r][1] = q; }
    }
    __syncthreads();
#pragma unroll
    for (int r = 0; r < 4; ++r) {
        const int row = quad * 4 + r;
        float S = 0.f, Q = 0.f;
#pragma unroll
        for (int ww = 0; ww < 8; ++ww) { S += stats[ww][row][0]; Q += stats[ww][row][1]; }
        const float mean = S * (1.f / 256.f);
        const float rstd = rsqrtf(Q * (1.f / 256.f) - mean * mean + 1e-5f);
#pragma unroll
        for (int j = 0; j < 2; ++j) {
            const int col = nh + j * 16 + colL;
            Acat[row][256 + col] = __float2bfloat16((acc[j][r] - mean) * rstd * gs[col] + bs_[col]);
        }
    }
    __syncthreads();   // Acat complete; phase-1 gs reads done

    // ---- phase 2: W1 + ReLU (K=512, A from Acat), h -> Hs ----
#pragma unroll 1
    for (int nc = 0; nc < 2; ++nc) {
#pragma unroll
        for (int j = 0; j < 2; ++j) acc[j] = (f32x4){0.f, 0.f, 0.f, 0.f};
        short8 rb[4];
#pragma unroll
        for (int p = 0; p < 4; ++p)
            rb[p] = *(const short8*)(W1_b + (size_t)(nc * 256 + srow + p * 64) * 512 + scg);
        for (int k0 = 0; k0 < 512; k0 += 64) {
            __syncthreads();
#pragma unroll
            for (int p = 0; p < 4; ++p)
                *(short8*)&Bs[srow + p * 64][scg] = rb[p];
            __syncthreads();
            if (k0 + 64 < 512) {
#pragma unroll
                for (int p = 0; p < 4; ++p)
                    rb[p] = *(const short8*)(W1_b + (size_t)(nc * 256 + srow + p * 64) * 512 + k0 + 64 + scg);
            }
#pragma unroll
            for (int ks = 0; ks < 2; ++ks) {
                short8 af = *(const short8*)&Acat[colL][k0 + ks * 32 + quad * 8];
#pragma unroll
                for (int j = 0; j < 2; ++j) {
                    short8 bf = *(const short8*)&Bs[nh + j * 16 + colL][ks * 32 + quad * 8];
                    acc[j] = __builtin_amdgcn_mfma_f32_16x16x32_bf16(af, bf, acc[j], 0, 0, 0);
                }
            }
        }
#pragma unroll
        for (int r = 0; r < 4; ++r) {
            const int row = quad * 4 + r;
#pragma unroll
            for (int j = 0; j < 2; ++j) {
                const int col = nc * 256 + nh + j * 16 + colL;
                Hs[row][col] = __float2bfloat16(fmaxf(acc[j][r], 0.f));
            }
        }
    }
    if (tid < 256) { gs[tid] = g2[tid]; bs_[tid] = b2[tid]; }  // next barrier orders use
    __syncthreads();   // Hs complete

    // ---- phase 3: W2 (K=512, A from Hs) + LN2 + residual -> out ----
#pragma unroll
    for (int j = 0; j < 2; ++j) acc[j] = (f32x4){0.f, 0.f, 0.f, 0.f};
    {
        short8 rb[4];
#pragma unroll
        for (int p = 0; p < 4; ++p)
            rb[p] = *(const short8*)(W2_b + (size_t)(srow + p * 64) * 512 + scg);
        for (int k0 = 0; k0 < 512; k0 += 64) {
            __syncthreads();
#pragma unroll
            for (int p = 0; p < 4; ++p)
                *(short8*)&Bs[srow + p * 64][scg] = rb[p];
            __syncthreads();
            if (k0 + 64 < 512) {
#pragma unroll
                for (int p = 0; p < 4; ++p)
                    rb[p] = *(const short8*)(W2_b + (size_t)(srow + p * 64) * 512 + k0 + 64 + scg);
            }
#pragma unroll
            for (int ks = 0; ks < 2; ++ks) {
                short8 af = *(const short8*)&Hs[colL][k0 + ks * 32 + quad * 8];
#pragma unroll
                for (int j = 0; j < 2; ++j) {
                    short8 bf = *(const short8*)&Bs[nh + j * 16 + colL][ks * 32 + quad * 8];
                    acc[j] = __builtin_amdgcn_mfma_f32_16x16x32_bf16(af, bf, acc[j], 0, 0, 0);
                }
            }
        }
    }
#pragma unroll
    for (int r = 0; r < 4; ++r) {
        float s = 0.f, q = 0.f;
#pragma unroll
        for (int j = 0; j < 2; ++j) { float v = acc[j][r]; s += v; q += v * v; }
        s += __shfl_xor(s, 1); q += __shfl_xor(q, 1);
        s += __shfl_xor(s, 2); q += __shfl_xor(q, 2);
        s += __shfl_xor(s, 4); q += __shfl_xor(q, 4);
        s += __shfl_xor(s, 8); q += __shfl_xor(q, 8);
        if (colL == 0) { stats[w][quad * 4 + r][0] = s; stats[w][quad * 4 + r][1] = q; }
    }
    __syncthreads();
#pragma unroll
    for (int r = 0; r < 4; ++r) {
        const int row = quad * 4 + r;
        float S = 0.f, Q = 0.f;
#pragma unroll
        for (int ww = 0; ww < 8; ++ww) { S += stats[ww][row][0]; Q += stats[ww][row][1]; }
        const float mean = S * (1.f / 256.f);
        const float rstd = rsqrtf(Q * (1.f / 256.f) - mean * mean + 1e-5f);
        const size_t grow = (size_t)(m0 + row) * 256;
#pragma unroll
        for (int j = 0; j < 2; ++j) {
            const int col = nh + j * 16 + colL;
            out[grow + col] = (acc[j][r] - mean) * rstd * gs[col] + bs_[col] + x[grow + col];
        }
    }
}

// ---------------------------------------------------------------------------
extern "C" void kernel_launch(void* const* d_in, const int* in_sizes, int n_in,
                              void* d_out, int out_size, void* d_ws, size_t ws_size,
                              hipStream_t stream) {
    (void)in_sizes; (void)n_in; (void)out_size; (void)ws_size;
    const float* x   = (const float*)d_in[0];
    const float* src = (const float*)d_in[1];
    const float* F   = (const float*)d_in[2];
    const float* Wq  = (const float*)d_in[3];
    const float* Wk  = (const float*)d_in[4];
    const float* Wv  = (const float*)d_in[5];
    const float* Wm  = (const float*)d_in[6];
    const float* W1  = (const float*)d_in[7];
    const float* W2  = (const float*)d_in[8];
    const float* g1  = (const float*)d_in[9];
    const float* b1  = (const float*)d_in[10];
    const float* g2  = (const float*)d_in[11];
    const float* b2  = (const float*)d_in[12];
    float* out = (float*)d_out;

    // Workspace (24 MB):
    //   [0,2M) x_b  [2M,4M) src_b  [4M,5.25M) weights bf16
    //   [6M,8M) Qb  [8M,10M) Kb  [10M,12M) Vtb
    //   [14M,18M) Opart (NSPLIT=2 x 2MB)  [22M,22.25M) Ll
    char* ws = (char*)d_ws;
    __hip_bfloat16* x_b   = (__hip_bfloat16*)(ws);
    __hip_bfloat16* src_b = (__hip_bfloat16*)(ws + (2u << 20));
    __hip_bfloat16* Wq_b  = (__hip_bfloat16*)(ws + (4u << 20));
    __hip_bfloat16* Wk_b  = (__hip_bfloat16*)(ws + (4u << 20) + 131072);
    __hip_bfloat16* Wv_b  = (__hip_bfloat16*)(ws + (4u << 20) + 2 * 131072);
    __hip_bfloat16* Wm_b  = (__hip_bfloat16*)(ws + (4u << 20) + 3 * 131072);
    __hip_bfloat16* W1_b  = (__hip_bfloat16*)(ws + (4u << 20) + 4 * 131072);
    __hip_bfloat16* W2_b  = (__hip_bfloat16*)(ws + (4u << 20) + 4 * 131072 + 524288);
    __hip_bfloat16* Qb   = (__hip_bfloat16*)(ws + (6u << 20));
    __hip_bfloat16* Kb   = (__hip_bfloat16*)(ws + (8u << 20));
    __hip_bfloat16* Vtb  = (__hip_bfloat16*)(ws + (10u << 20));
    __hip_bfloat16* Opart = (__hip_bfloat16*)(ws + (14u << 20));
    float* Ll  = (float*)(ws + (22u << 20));

    dim3 blk(256);
    convert_all<<<dim3(2688), blk, 0, stream>>>(x, src, Wq, Wk, Wv, Wm, W1, W2,
                                                x_b, src_b, Wq_b, Wk_b, Wv_b, Wm_b, W1_b, W2_b);
    // Fused Q/K/Vt projections: 128x64 tiles, 384 blocks
    proj_fused<<<dim3(384), blk, 0, stream>>>(x_b, src_b, Wq_b, Wk_b, Wv_b, Qb, Kb, Vtb);
    // Attention: split-S partials, NSPLIT=2 (1024 blocks)
    attn_mfma<<<dim3(L_ / 64, H_, B_ * NSPLIT), blk, 0, stream>>>(Qb, Kb, Vtb, F, Opart, Ll);
    // Combine + Wm + LN1 + W1 + ReLU + W2 + LN2 + residual (r3 staged-512)
    mlp_fused<<<dim3(ML_ / 16), dim3(512), 0, stream>>>(Opart, Ll, x_b, Wm_b, W1_b, W2_b,
                                                        g1, b1, g2, b2, x, out);
}

// Round 9
// 157.973 us; speedup vs baseline: 1.0209x; 1.0209x over previous
//
#include <hip/hip_runtime.h>
#include <hip/hip_bf16.h>
#include <math.h>

// Problem constants
#define B_  2
#define L_  2048
#define S_  2048
#define D_  256
#define H_  8
#define HD_ 32
#define ML_ (B_ * L_)
#define MS_ (B_ * S_)
#define NSPLIT 2
#define SCHUNK (S_ / NSPLIT)   // 1024

typedef __attribute__((ext_vector_type(8))) short short8;   // 8 bf16 (A/B frag)
typedef __attribute__((ext_vector_type(4))) float f32x4;    // C/D frag

// ---------------------------------------------------------------------------
// One-shot fp32 -> bf16 conversion of all GEMM operands. (Proven path:
// in-staging cvt (r16) forced vmcnt(0) drains -> serialized K-steps; direct
// global B-loads (r17) lost to staged LDS broadcast. Keep this kernel.)
// ---------------------------------------------------------------------------
__global__ __launch_bounds__(256) void convert_all(
    const float* __restrict__ x,  const float* __restrict__ src,
    const float* __restrict__ Wq, const float* __restrict__ Wk,
    const float* __restrict__ Wv, const float* __restrict__ Wm,
    const float* __restrict__ W1, const float* __restrict__ W2,
    __hip_bfloat16* xb,  __hip_bfloat16* srcb,
    __hip_bfloat16* Wqb, __hip_bfloat16* Wkb,
    __hip_bfloat16* Wvb, __hip_bfloat16* Wmb,
    __hip_bfloat16* W1b, __hip_bfloat16* W2b) {
    const size_t i4 = ((size_t)blockIdx.x * 256 + threadIdx.x) * 4;
    const float* sp; __hip_bfloat16* dp; size_t off;
    if      (i4 < 1048576) { sp = x;   dp = xb;   off = i4; }
    else if (i4 < 2097152) { sp = src; dp = srcb; off = i4 - 1048576; }
    else if (i4 < 2162688) { sp = Wq;  dp = Wqb;  off = i4 - 2097152; }
    else if (i4 < 2228224) { sp = Wk;  dp = Wkb;  off = i4 - 2162688; }
    else if (i4 < 2293760) { sp = Wv;  dp = Wvb;  off = i4 - 2228224; }
    else if (i4 < 2359296) { sp = Wm;  dp = Wmb;  off = i4 - 2293760; }
    else if (i4 < 2621440) { sp = W1;  dp = W1b;  off = i4 - 2359296; }
    else                   { sp = W2;  dp = W2b;  off = i4 - 2621440; }
    float4 v = *(const float4*)(sp + off);
    __hip_bfloat16 o0 = __float2bfloat16(v.x), o1 = __float2bfloat16(v.y);
    __hip_bfloat16 o2 = __float2bfloat16(v.z), o3 = __float2bfloat16(v.w);
    __hip_bfloat16* d = dp + off;
    d[0] = o0; d[1] = o1; d[2] = o2; d[3] = o3;
}

// ---------------------------------------------------------------------------
// Shared bf16 MFMA GEMM body (64x64 tile, 4 waves). cscale in epilogue.
// Proven optimum for proj: 128x64 tiles (r19) lost ~2us to makespan
// lumpiness (384 blocks = 1.5 residency rounds with a half-empty tail).
// ---------------------------------------------------------------------------
template <bool RELU, typename OutT>
__device__ __forceinline__ void gemm_body(const __hip_bfloat16* __restrict__ A,
                                          const __hip_bfloat16* __restrict__ Bm,
                                          OutT* __restrict__ C,
                                          int N, int K, int lda, int m0, int n0,
                                          float cscale,
                                          __hip_bfloat16 (&As)[64][72],
                                          __hip_bfloat16 (&Bs)[64][72]) {
    const int tid  = threadIdx.x;
    const int w    = tid >> 6;
    const int lane = tid & 63;
    const int colL = lane & 15;
    const int quad = lane >> 4;
    const int mh = (w & 1) * 32, nh = (w >> 1) * 32;
    const int srow = tid >> 3;
    const int scg  = (tid & 7) * 8;

    f32x4 acc[2][2] = {};

    auto loadA = [&](int p, int k0) -> short8 {
        return *(const short8*)(A + (size_t)(m0 + srow + p * 32) * lda + k0 + scg);
    };
    auto loadB = [&](int p, int k0) -> short8 {
        return *(const short8*)(Bm + (size_t)(n0 + srow + p * 32) * K + k0 + scg);
    };

    short8 ra[2], rb[2];
#pragma unroll
    for (int p = 0; p < 2; ++p) { ra[p] = loadA(p, 0); rb[p] = loadB(p, 0); }

    for (int k0 = 0; k0 < K; k0 += 64) {
        __syncthreads();
#pragma unroll
        for (int p = 0; p < 2; ++p) {
            *(short8*)&As[srow + p * 32][scg] = ra[p];
            *(short8*)&Bs[srow + p * 32][scg] = rb[p];
        }
        __syncthreads();
        if (k0 + 64 < K) {
#pragma unroll
            for (int p = 0; p < 2; ++p) { ra[p] = loadA(p, k0 + 64); rb[p] = loadB(p, k0 + 64); }
        }
#pragma unroll
        for (int ks = 0; ks < 2; ++ks) {
            short8 af[2], bf[2];
#pragma unroll
            for (int i = 0; i < 2; ++i)
                af[i] = *(const short8*)&As[mh + i * 16 + colL][ks * 32 + quad * 8];
#pragma unroll
            for (int j = 0; j < 2; ++j)
                bf[j] = *(const short8*)&Bs[nh + j * 16 + colL][ks * 32 + quad * 8];
#pragma unroll
            for (int i = 0; i < 2; ++i)
#pragma unroll
                for (int j = 0; j < 2; ++j)
                    acc[i][j] = __builtin_amdgcn_mfma_f32_16x16x32_bf16(af[i], bf[j], acc[i][j], 0, 0, 0);
        }
    }
#pragma unroll
    for (int i = 0; i < 2; ++i)
#pragma unroll
        for (int r = 0; r < 4; ++r) {
            const size_t row = m0 + mh + i * 16 + quad * 4 + r;
#pragma unroll
            for (int j = 0; j < 2; ++j) {
                float v = acc[i][j][r] * cscale;
                if (RELU) v = fmaxf(v, 0.f);
                C[row * N + n0 + nh + j * 16 + colL] = (OutT)v;
            }
        }
}

// ---------------------------------------------------------------------------
// Fused Q/K/Vt projection GEMMs (bf16 staged, proven). Q pre-scaled by
// 1/sqrt(hd). Grid 768 (no junk blocks).
// ---------------------------------------------------------------------------
__global__ __launch_bounds__(256) void proj_fused(const __hip_bfloat16* __restrict__ x_b,
                                                  const __hip_bfloat16* __restrict__ src_b,
                                                  const __hip_bfloat16* __restrict__ Wq_b,
                                                  const __hip_bfloat16* __restrict__ Wk_b,
                                                  const __hip_bfloat16* __restrict__ Wv_b,
                                                  __hip_bfloat16* __restrict__ Qb,
                                                  __hip_bfloat16* __restrict__ Kb,
                                                  __hip_bfloat16* __restrict__ Vtb) {
    __shared__ __hip_bfloat16 As[64][72];
    __shared__ __hip_bfloat16 Bs[64][72];
    const int id = blockIdx.x;
    if (id < 256) {
        gemm_body<false, __hip_bfloat16>(x_b, Wq_b, Qb, 256, 256, 256,
                                         (id >> 2) * 64, (id & 3) * 64,
                                         0.17677669529663687f, As, Bs);
    } else if (id < 512) {
        const int t = id - 256;
        gemm_body<false, __hip_bfloat16>(src_b, Wk_b, Kb, 256, 256, 256,
                                         (t >> 2) * 64, (t & 3) * 64, 1.f, As, Bs);
    } else {
        const int t = id - 512;           // 0..255 (grid 768: only real blocks)
        const int b = t >> 7, u = t & 127;
        gemm_body<false, __hip_bfloat16>(Wv_b, src_b + (size_t)b * S_ * D_,
                                         Vtb + (size_t)b * D_ * S_, S_, 256, 256,
                                         (u & 3) * 64, (u >> 2) * 64, 1.f, As, Bs);
    }
}

// ---------------------------------------------------------------------------
// Flash attention — round-0 proven inner loop, NSPLIT=2 (neutral vs 4).
// Inner loop untouched (structural attn edits regressed 3.4x in r14).
// ---------------------------------------------------------------------------
__global__ __launch_bounds__(256, 4) void attn_mfma(const __hip_bfloat16* __restrict__ Qb,
                                                    const __hip_bfloat16* __restrict__ Kb,
                                                    const __hip_bfloat16* __restrict__ Vtb,
                                                    const float* __restrict__ F,
                                                    __hip_bfloat16* __restrict__ Op,
                                                    float* __restrict__ Ll) {
    const int tid  = threadIdx.x;
    const int w    = tid >> 6;
    const int lane = tid & 63;
    const int colL = lane & 15;
    const int quad = lane >> 4;

    const int b     = blockIdx.z / NSPLIT;
    const int split = blockIdx.z % NSPLIT;
    const int h     = blockIdx.y;
    const int qw    = blockIdx.x * 64 + w * 16;

    __shared__ __hip_bfloat16 Ks[128][40];
    __shared__ __hip_bfloat16 Vs[32][136];
    __shared__ __hip_bfloat16 Pw[4][16][72];

    const short8 aq = *(const short8*)(Qb + ((size_t)(b * L_ + qw + colL)) * D_ + h * HD_ + quad * 8);

    float lsum[4] = {0.f, 0.f, 0.f, 0.f};
    f32x4 o0 = {0.f, 0.f, 0.f, 0.f}, o1 = {0.f, 0.f, 0.f, 0.f};

    const int kr = tid >> 2, kc = (tid & 3) * 8;
    const int vr = tid >> 3, vc = (tid & 7) * 8;
    const __hip_bfloat16* kst = Kb + ((size_t)(b * S_ + kr)) * D_ + h * HD_ + kc;
    const __hip_bfloat16* vst = Vtb + (size_t)b * D_ * S_ + ((size_t)(h * HD_ + vr)) * S_ + vc;
    const float* fbase = F + ((size_t)(b * L_ + qw + quad * 4)) * S_ + colL;

    const int sbeg = split * SCHUNK, send = sbeg + SCHUNK;
    short8 rk[2], rv[2];
#pragma unroll
    for (int p = 0; p < 2; ++p) {
        rk[p] = *(const short8*)(kst + (size_t)(sbeg + p * 64) * D_);
        rv[p] = *(const short8*)(vst + sbeg + p * 64);
    }

    for (int s0 = sbeg; s0 < send; s0 += 128) {
        __syncthreads();
        *(short8*)&Ks[kr][kc]        = rk[0];
        *(short8*)&Ks[kr + 64][kc]   = rk[1];
        *(short8*)&Vs[vr][vc]        = rv[0];
        *(short8*)&Vs[vr][vc + 64]   = rv[1];
        __syncthreads();
        if (s0 + 128 < send) {
#pragma unroll
            for (int p = 0; p < 2; ++p) {
                rk[p] = *(const short8*)(kst + (size_t)(s0 + 128 + p * 64) * D_);
                rv[p] = *(const short8*)(vst + s0 + 128 + p * 64);
            }
        }
#pragma unroll
        for (int hs = 0; hs < 2; ++hs) {
            const int sh = s0 + hs * 64;
            f32x4 cc[4];
#pragma unroll
            for (int n = 0; n < 4; ++n) {
                short8 kf = *(const short8*)&Ks[hs * 64 + n * 16 + colL][quad * 8];
                f32x4 z = {0.f, 0.f, 0.f, 0.f};
                cc[n] = __builtin_amdgcn_mfma_f32_16x16x32_bf16(aq, kf, z, 0, 0, 0);
            }
#pragma unroll
            for (int n = 0; n < 4; ++n)
#pragma unroll
                for (int r = 0; r < 4; ++r) {
                    float fv = fbase[(size_t)r * S_ + sh + n * 16];
                    float p = __expf(cc[n][r] * fv);
                    lsum[r] += p;
                    Pw[w][quad * 4 + r][n * 16 + colL] = __float2bfloat16(p);
                }
            short8 a0 = *(const short8*)(&Pw[w][colL][quad * 8]);
            short8 a1 = *(const short8*)(&Pw[w][colL][32 + quad * 8]);
#pragma unroll
            for (int ks = 0; ks < 2; ++ks) {
                short8 ap = ks ? a1 : a0;
#pragma unroll
                for (int nt = 0; nt < 2; ++nt) {
                    short8 vf = *(const short8*)&Vs[nt * 16 + colL][hs * 64 + ks * 32 + quad * 8];
                    if (nt == 0) o0 = __builtin_amdgcn_mfma_f32_16x16x32_bf16(ap, vf, o0, 0, 0, 0);
                    else         o1 = __builtin_amdgcn_mfma_f32_16x16x32_bf16(ap, vf, o1, 0, 0, 0);
                }
            }
        }
    }

#pragma unroll
    for (int r = 0; r < 4; ++r) {
        float t = lsum[r];
        t += __shfl_xor(t, 1);
        t += __shfl_xor(t, 2);
        t += __shfl_xor(t, 4);
        t += __shfl_xor(t, 8);
        lsum[r] = t;
    }

#pragma unroll
    for (int r = 0; r < 4; ++r) {
        const size_t row = (size_t)(b * L_ + qw + quad * 4 + r);
        const size_t po = ((size_t)split * ML_ + row) * D_ + h * HD_;
        Op[po + colL]      = __float2bfloat16(o0[r]);
        Op[po + 16 + colL] = __float2bfloat16(o1[r]);
        if (colL == 0)
            Ll[((size_t)split * H_ + h) * ML_ + row] = lsum[r];
    }
}

// ---------------------------------------------------------------------------
// MLP megakernel — proven staged version (512 threads / 8 waves). Its local
// optimum: more waves (r15) neutral, in-staging cvt (r16) and barrier-free
// direct B-loads (r17) both regressed. Per block 16 rows, three phases:
//   P1: combine Opart (+1/sumLl) -> Wm GEMM -> LN1 -> Acat[:,256:512]
//   P2: W1 GEMM + ReLU over K=512 (A from LDS Acat, B staged) -> Hs
//   P3: W2 GEMM over K=512 (A from Hs) + LN2 + residual -> out (fp32)
// ---------------------------------------------------------------------------
__global__ __launch_bounds__(512) void mlp_fused(const __hip_bfloat16* __restrict__ Opart,
                                                 const float* __restrict__ Ll,
                                                 const __hip_bfloat16* __restrict__ x_b,
                                                 const __hip_bfloat16* __restrict__ Wm_b,
                                                 const __hip_bfloat16* __restrict__ W1_b,
                                                 const __hip_bfloat16* __restrict__ W2_b,
                                                 const float* __restrict__ g1,
                                                 const float* __restrict__ b1,
                                                 const float* __restrict__ g2,
                                                 const float* __restrict__ b2,
                                                 const float* __restrict__ x,
                                                 float* __restrict__ out) {
    __shared__ __hip_bfloat16 Bs[256][72];     // 36864 B (shared by all phases)
    __shared__ __hip_bfloat16 As[16][72];      // 2304 B  (phase-1 A staging)
    __shared__ __hip_bfloat16 Acat[16][520];   // 16640 B [x | m1]
    __shared__ __hip_bfloat16 Hs[16][520];     // 16640 B h (512 cols used)
    __shared__ float gs[256], bs_[256];
    __shared__ float stats[8][16][2];
    __shared__ float Linv[16][8];

    const int tid  = threadIdx.x;
    const int w    = tid >> 6;        // 0..7
    const int lane = tid & 63;
    const int colL = lane & 15;
    const int quad = lane >> 4;
    const int nh   = w * 32;          // per-wave 32-col slice
    const int m0   = blockIdx.x * 16;
    const int srow = tid >> 3;        // 0..63
    const int scg  = (tid & 7) * 8;   // 0..56

    // ---- phase 0: params, Linv, x rows -> Acat[:,0:256] ----
    if (tid < 256) { gs[tid] = g1[tid]; bs_[tid] = b1[tid]; }
    if (tid < 128) {
        const int row = tid >> 3, hh = tid & 7;
        float t = 0.f;
#pragma unroll
        for (int s = 0; s < NSPLIT; ++s)
            t += Ll[((size_t)s * H_ + hh) * ML_ + m0 + row];
        Linv[row][hh] = 1.f / t;
    }
    if (tid < 256) {
        const int xr = tid >> 4, xc = (tid & 15) * 16;
        *(short8*)&Acat[xr][xc]     = *(const short8*)(x_b + (size_t)(m0 + xr) * 256 + xc);
        *(short8*)&Acat[xr][xc + 8] = *(const short8*)(x_b + (size_t)(m0 + xr) * 256 + xc + 8);
    }
    __syncthreads();

    // ---- phase 1: combine + Wm GEMM (K=256) ----
    f32x4 acc[2] = {};
    auto loadA1 = [&](int k0) -> short8 {     // srow < 16 only (tid < 128)
        const float inv = Linv[srow][(k0 + scg) >> 5];
        float a[8] = {};
#pragma unroll
        for (int s = 0; s < NSPLIT; ++s) {
            short8 v = *(const short8*)(Opart + ((size_t)s * ML_ + m0 + srow) * 256 + k0 + scg);
#pragma unroll
            for (int e = 0; e < 8; ++e) {
                union { short s16; __hip_bfloat16 h; } c; c.s16 = v[e];
                a[e] += __bfloat162float(c.h);
            }
        }
        short8 outv;
#pragma unroll
        for (int e = 0; e < 8; ++e) {
            union { __hip_bfloat16 h; short s16; } c;
            c.h = __float2bfloat16(a[e] * inv);
            outv[e] = c.s16;
        }
        return outv;
    };

    {
        short8 ra = {};
        if (srow < 16) ra = loadA1(0);
        short8 rb[4];
#pragma unroll
        for (int p = 0; p < 4; ++p)
            rb[p] = *(const short8*)(Wm_b + (size_t)(srow + p * 64) * 256 + scg);
        for (int k0 = 0; k0 < 256; k0 += 64) {
            __syncthreads();
            if (srow < 16) *(short8*)&As[srow][scg] = ra;
#pragma unroll
            for (int p = 0; p < 4; ++p)
                *(short8*)&Bs[srow + p * 64][scg] = rb[p];
            __syncthreads();
            if (k0 + 64 < 256) {
                if (srow < 16) ra = loadA1(k0 + 64);
#pragma unroll
                for (int p = 0; p < 4; ++p)
                    rb[p] = *(const short8*)(Wm_b + (size_t)(srow + p * 64) * 256 + k0 + 64 + scg);
            }
#pragma unroll
            for (int ks = 0; ks < 2; ++ks) {
                short8 af = *(const short8*)&As[colL][ks * 32 + quad * 8];
#pragma unroll
                for (int j = 0; j < 2; ++j) {
                    short8 bf = *(const short8*)&Bs[nh + j * 16 + colL][ks * 32 + quad * 8];
                    acc[j] = __builtin_amdgcn_mfma_f32_16x16x32_bf16(af, bf, acc[j], 0, 0, 0);
                }
            }
        }
    }
    // LN1 stats + write m1 into Acat[:,256:512]
#pragma unroll
    for (int r = 0; r < 4; ++r) {
        float s = 0.f, q = 0.f;
#pragma unroll
        for (int j = 0; j < 2; ++j) { float v = acc[j][r]; s += v; q += v * v; }
        s += __shfl_xor(s, 1); q += __shfl_xor(q, 1);
        s += __shfl_xor(s, 2); q += __shfl_xor(q, 2);
        s += __shfl_xor(s, 4); q += __shfl_xor(q, 4);
        s += __shfl_xor(s, 8); q += __shfl_xor(q, 8);
        if (colL == 0) { stats[w][quad * 4 + r][0] = s; stats[w][quad * 4 + r][1] = q; }
    }
    __syncthreads();
#pragma unroll
    for (int r = 0; r < 4; ++r) {
        const int row = quad * 4 + r;
        float S = 0.f, Q = 0.f;
#pragma unroll
        for (int ww = 0; ww < 8; ++ww) { S += stats[ww][row][0]; Q += stats[ww][row][1]; }
        const float mean = S * (1.f / 256.f);
        const float rstd = rsqrtf(Q * (1.f / 256.f) - mean * mean + 1e-5f);
#pragma unroll
        for (int j = 0; j < 2; ++j) {
            const int col = nh + j * 16 + colL;
            Acat[row][256 + col] = __float2bfloat16((acc[j][r] - mean) * rstd * gs[col] + bs_[col]);
        }
    }
    __syncthreads();   // Acat complete; phase-1 gs reads done

    // ---- phase 2: W1 + ReLU (K=512, A from Acat), h -> Hs ----
#pragma unroll 1
    for (int nc = 0; nc < 2; ++nc) {
#pragma unroll
        for (int j = 0; j < 2; ++j) acc[j] = (f32x4){0.f, 0.f, 0.f, 0.f};
        short8 rb[4];
#pragma unroll
        for (int p = 0; p < 4; ++p)
            rb[p] = *(const short8*)(W1_b + (size_t)(nc * 256 + srow + p * 64) * 512 + scg);
        for (int k0 = 0; k0 < 512; k0 += 64) {
            __syncthreads();
#pragma unroll
            for (int p = 0; p < 4; ++p)
                *(short8*)&Bs[srow + p * 64][scg] = rb[p];
            __syncthreads();
            if (k0 + 64 < 512) {
#pragma unroll
                for (int p = 0; p < 4; ++p)
                    rb[p] = *(const short8*)(W1_b + (size_t)(nc * 256 + srow + p * 64) * 512 + k0 + 64 + scg);
            }
#pragma unroll
            for (int ks = 0; ks < 2; ++ks) {
                short8 af = *(const short8*)&Acat[colL][k0 + ks * 32 + quad * 8];
#pragma unroll
                for (int j = 0; j < 2; ++j) {
                    short8 bf = *(const short8*)&Bs[nh + j * 16 + colL][ks * 32 + quad * 8];
                    acc[j] = __builtin_amdgcn_mfma_f32_16x16x32_bf16(af, bf, acc[j], 0, 0, 0);
                }
            }
        }
#pragma unroll
        for (int r = 0; r < 4; ++r) {
            const int row = quad * 4 + r;
#pragma unroll
            for (int j = 0; j < 2; ++j) {
                const int col = nc * 256 + nh + j * 16 + colL;
                Hs[row][col] = __float2bfloat16(fmaxf(acc[j][r], 0.f));
            }
        }
    }
    if (tid < 256) { gs[tid] = g2[tid]; bs_[tid] = b2[tid]; }  // next barrier orders use
    __syncthreads();   // Hs complete

    // ---- phase 3: W2 (K=512, A from Hs) + LN2 + residual -> out ----
#pragma unroll
    for (int j = 0; j < 2; ++j) acc[j] = (f32x4){0.f, 0.f, 0.f, 0.f};
    {
        short8 rb[4];
#pragma unroll
        for (int p = 0; p < 4; ++p)
            rb[p] = *(const short8*)(W2_b + (size_t)(srow + p * 64) * 512 + scg);
        for (int k0 = 0; k0 < 512; k0 += 64) {
            __syncthreads();
#pragma unroll
            for (int p = 0; p < 4; ++p)
                *(short8*)&Bs[srow + p * 64][scg] = rb[p];
            __syncthreads();
            if (k0 + 64 < 512) {
#pragma unroll
                for (int p = 0; p < 4; ++p)
                    rb[p] = *(const short8*)(W2_b + (size_t)(srow + p * 64) * 512 + k0 + 64 + scg);
            }
#pragma unroll
            for (int ks = 0; ks < 2; ++ks) {
                short8 af = *(const short8*)&Hs[colL][k0 + ks * 32 + quad * 8];
#pragma unroll
                for (int j = 0; j < 2; ++j) {
                    short8 bf = *(const short8*)&Bs[nh + j * 16 + colL][ks * 32 + quad * 8];
                    acc[j] = __builtin_amdgcn_mfma_f32_16x16x32_bf16(af, bf, acc[j], 0, 0, 0);
                }
            }
        }
    }
#pragma unroll
    for (int r = 0; r < 4; ++r) {
        float s = 0.f, q = 0.f;
#pragma unroll
        for (int j = 0; j < 2; ++j) { float v = acc[j][r]; s += v; q += v * v; }
        s += __shfl_xor(s, 1); q += __shfl_xor(q, 1);
        s += __shfl_xor(s, 2); q += __shfl_xor(q, 2);
        s += __shfl_xor(s, 4); q += __shfl_xor(q, 4);
        s += __shfl_xor(s, 8); q += __shfl_xor(q, 8);
        if (colL == 0) { stats[w][quad * 4 + r][0] = s; stats[w][quad * 4 + r][1] = q; }
    }
    __syncthreads();
#pragma unroll
    for (int r = 0; r < 4; ++r) {
        const int row = quad * 4 + r;
        float S = 0.f, Q = 0.f;
#pragma unroll
        for (int ww = 0; ww < 8; ++ww) { S += stats[ww][row][0]; Q += stats[ww][row][1]; }
        const float mean = S * (1.f / 256.f);
        const float rstd = rsqrtf(Q * (1.f / 256.f) - mean * mean + 1e-5f);
        const size_t grow = (size_t)(m0 + row) * 256;
#pragma unroll
        for (int j = 0; j < 2; ++j) {
            const int col = nh + j * 16 + colL;
            out[grow + col] = (acc[j][r] - mean) * rstd * gs[col] + bs_[col] + x[grow + col];
        }
    }
}

// ---------------------------------------------------------------------------
extern "C" void kernel_launch(void* const* d_in, const int* in_sizes, int n_in,
                              void* d_out, int out_size, void* d_ws, size_t ws_size,
                              hipStream_t stream) {
    (void)in_sizes; (void)n_in; (void)out_size; (void)ws_size;
    const float* x   = (const float*)d_in[0];
    const float* src = (const float*)d_in[1];
    const float* F   = (const float*)d_in[2];
    const float* Wq  = (const float*)d_in[3];
    const float* Wk  = (const float*)d_in[4];
    const float* Wv  = (const float*)d_in[5];
    const float* Wm  = (const float*)d_in[6];
    const float* W1  = (const float*)d_in[7];
    const float* W2  = (const float*)d_in[8];
    const float* g1  = (const float*)d_in[9];
    const float* b1  = (const float*)d_in[10];
    const float* g2  = (const float*)d_in[11];
    const float* b2  = (const float*)d_in[12];
    float* out = (float*)d_out;

    // Workspace (24 MB):
    //   [0,2M) x_b  [2M,4M) src_b  [4M,5.25M) weights bf16
    //   [6M,8M) Qb  [8M,10M) Kb  [10M,12M) Vtb
    //   [14M,18M) Opart (NSPLIT=2 x 2MB)  [22M,22.25M) Ll
    char* ws = (char*)d_ws;
    __hip_bfloat16* x_b   = (__hip_bfloat16*)(ws);
    __hip_bfloat16* src_b = (__hip_bfloat16*)(ws + (2u << 20));
    __hip_bfloat16* Wq_b  = (__hip_bfloat16*)(ws + (4u << 20));
    __hip_bfloat16* Wk_b  = (__hip_bfloat16*)(ws + (4u << 20) + 131072);
    __hip_bfloat16* Wv_b  = (__hip_bfloat16*)(ws + (4u << 20) + 2 * 131072);
    __hip_bfloat16* Wm_b  = (__hip_bfloat16*)(ws + (4u << 20) + 3 * 131072);
    __hip_bfloat16* W1_b  = (__hip_bfloat16*)(ws + (4u << 20) + 4 * 131072);
    __hip_bfloat16* W2_b  = (__hip_bfloat16*)(ws + (4u << 20) + 4 * 131072 + 524288);
    __hip_bfloat16* Qb   = (__hip_bfloat16*)(ws + (6u << 20));
    __hip_bfloat16* Kb   = (__hip_bfloat16*)(ws + (8u << 20));
    __hip_bfloat16* Vtb  = (__hip_bfloat16*)(ws + (10u << 20));
    __hip_bfloat16* Opart = (__hip_bfloat16*)(ws + (14u << 20));
    float* Ll  = (float*)(ws + (22u << 20));

    dim3 blk(256);
    convert_all<<<dim3(2688), blk, 0, stream>>>(x, src, Wq, Wk, Wv, Wm, W1, W2,
                                                x_b, src_b, Wq_b, Wk_b, Wv_b, Wm_b, W1_b, W2_b);
    // Fused Q/K/Vt projections (Q pre-scaled by 1/sqrt(hd)); 768 real blocks
    proj_fused<<<dim3(768), blk, 0, stream>>>(x_b, src_b, Wq_b, Wk_b, Wv_b, Qb, Kb, Vtb);
    // Attention: split-S partials, NSPLIT=2 (1024 blocks)
    attn_mfma<<<dim3(L_ / 64, H_, B_ * NSPLIT), blk, 0, stream>>>(Qb, Kb, Vtb, F, Opart, Ll);
    // Combine + Wm + LN1 + W1 + ReLU + W2 + LN2 + residual (staged-512)
    mlp_fused<<<dim3(ML_ / 16), dim3(512), 0, stream>>>(Opart, Ll, x_b, Wm_b, W1_b, W2_b,
                                                        g1, b1, g2, b2, x, out);
}